// Round 8
// baseline (405.471 us; speedup 1.0000x reference)
//
#include <hip/hip_runtime.h>
#include <hip/hip_bf16.h>

typedef float f32x4 __attribute__((ext_vector_type(4)));
typedef __bf16 bf16x8 __attribute__((ext_vector_type(8)));

#define H 1024
#define II 4096
#define NE 16
#define CAP 1024
#define NTOK 2048
#define NSLOT 4096

__device__ __forceinline__ void gload16(const void* g, void* l) {
  __builtin_amdgcn_global_load_lds(
      (const __attribute__((address_space(1))) unsigned*)g,
      (__attribute__((address_space(3))) unsigned*)l, 16, 0, 0);
}

// ---------------- routing ----------------
__global__ __launch_bounds__(256) void k_route(
    const float* __restrict__ x, const float* __restrict__ gw,
    const float* __restrict__ erw, int* __restrict__ eid,
    float* __restrict__ wgt) {
  int t = blockIdx.x * 4 + (threadIdx.x >> 6);
  int lane = threadIdx.x & 63;
  const float* xr = x + (size_t)t * H;
  double acc[20];
#pragma unroll
  for (int j = 0; j < 20; j++) acc[j] = 0.0;
  for (int it = 0; it < 16; ++it) {
    int h = it * 64 + lane;
    float xv = xr[h];
#pragma unroll
    for (int g = 0; g < 4; ++g) acc[g] += (double)xv * (double)gw[g * H + h];
#pragma unroll
    for (int j = 0; j < 16; ++j)
      acc[4 + j] += (double)xv * (double)erw[j * H + h];
  }
#pragma unroll
  for (int j = 0; j < 20; ++j) {
    double v = acc[j];
#pragma unroll
    for (int o = 32; o > 0; o >>= 1) v += __shfl_down(v, o, 64);
    acc[j] = v;
  }
  if (lane == 0) {
    float gl[4];
#pragma unroll
    for (int g = 0; g < 4; g++) gl[g] = (float)acc[g];
    int g1 = 0;
#pragma unroll
    for (int g = 1; g < 4; g++)
      if (gl[g] > gl[g1]) g1 = g;
    int g2 = (g1 == 0) ? 1 : 0;
#pragma unroll
    for (int g = 0; g < 4; g++)
      if (g != g1 && gl[g] > gl[g2]) g2 = g;
    float gm = fmaxf(fmaxf(gl[0], gl[1]), fmaxf(gl[2], gl[3]));
    float s = 0.f;
#pragma unroll
    for (int g = 0; g < 4; g++) s += expf(gl[g] - gm);
    float p[2] = {expf(gl[g1] - gm) / s, expf(gl[g2] - gm) / s};
    int gs[2] = {g1, g2};
#pragma unroll
    for (int k = 0; k < 2; k++) {
      int g = gs[k];
      float el[4];
#pragma unroll
      for (int e2 = 0; e2 < 4; e2++) el[e2] = (float)acc[4 + g * 4 + e2];
      int eb = 0;
#pragma unroll
      for (int e2 = 1; e2 < 4; e2++)
        if (el[e2] > el[eb]) eb = e2;
      float es = 0.f;
#pragma unroll
      for (int e2 = 0; e2 < 4; e2++) es += expf(el[e2] - el[eb]);
      eid[2 * t + k] = g * 4 + eb;
      wgt[2 * t + k] = p[k] * (1.f / es);
    }
  }
}

// ---------------- capacity scan ----------------
__global__ __launch_bounds__(1024) void k_scan(const int* __restrict__ eid,
                                               int* __restrict__ perm,
                                               int* __restrict__ cnt,
                                               int* __restrict__ kept) {
  int wid = threadIdx.x >> 6;
  int lane = threadIdx.x & 63;
  int ne[64];
#pragma unroll
  for (int it = 0; it < 64; ++it) ne[it] = eid[it * 64 + lane];
  int base = 0;
#pragma unroll
  for (int it = 0; it < 64; ++it) {
    int slot = it * 64 + lane;
    int e = ne[it];
    unsigned long long m = __ballot(e == wid);
    if (e == wid) {
      int pos = base + __popcll(m & ((1ull << lane) - 1ull));
      if (pos < CAP) {
        perm[wid * CAP + pos] = slot;
        kept[slot] = 1;
      } else {
        kept[slot] = 0;
      }
    }
    base += __popcll(m);
  }
  if (lane == 0) cnt[wid] = (base < CAP) ? base : CAP;
}

// ---------------- x -> bf16 ----------------
__global__ __launch_bounds__(256) void k_cvtx(const float* __restrict__ x,
                                              __bf16* __restrict__ xb) {
  size_t i = ((size_t)blockIdx.x * 256 + threadIdx.x) * 8;
  f32x4 a = *(const f32x4*)(x + i);
  f32x4 b = *(const f32x4*)(x + i + 4);
  bf16x8 o;
#pragma unroll
  for (int j = 0; j < 4; j++) {
    o[j] = (__bf16)a[j];
    o[j + 4] = (__bf16)b[j];
  }
  *(bf16x8*)(xb + i) = o;
}

#define VMCNT(N) asm volatile("s_waitcnt vmcnt(" #N ")" ::: "memory")
#define LGK0 asm volatile("s_waitcnt lgkmcnt(0)" ::: "memory")
#define SBAR()                           \
  __builtin_amdgcn_sched_barrier(0);     \
  __builtin_amdgcn_s_barrier();          \
  __builtin_amdgcn_sched_barrier(0);

#define MFMA_BF16(A, B, C) __builtin_amdgcn_mfma_f32_16x16x32_bf16(A, B, C, 0, 0, 0)

// ---------------- pass 1: act = silu(x@Wg^T) * (x@Wu^T) ----------
// BM=128, BN=64(G)+64(U), BK=32, 256 thr (2m x 2n waves).
// global_load_lds direct staging (A bf16, G/U fp32), counted vmcnt(6),
// XOR-swizzled global src + swizzled LDS read, cvt fp32->bf16 at frag read.
__global__ __launch_bounds__(256, 3) void k_gateup(
    const __bf16* __restrict__ xb, const float* __restrict__ Wg,
    const float* __restrict__ Wu, const int* __restrict__ perm,
    const int* __restrict__ cnt, __bf16* __restrict__ act) {
  __shared__ __bf16 As[2][128 * 32];
  __shared__ float Gs[2][64 * 32];
  __shared__ float Us[2][64 * 32];
  __shared__ int slotArr[128];
  const int e = blockIdx.z, nt = blockIdx.x, rt = blockIdx.y;
  const int ce = cnt[e];
  if (ce <= 0 || rt * 128 >= ce) return;
  const int tid = threadIdx.x, lane = tid & 63, w = tid >> 6;
  if (tid < 128) {
    int ridx = rt * 128 + tid;
    slotArr[tid] = perm[e * CAP + (ridx < ce ? ridx : 0)];
  }
  __syncthreads();
  // per-lane staging sources (inverse-swizzled). Wave w: A rows 32w..32w+31
  // (two 16-row instrs), G/U rows 16w..16w+15 (two 8-row instrs each).
  const int rA0 = 32 * w + (lane >> 2), rA1 = rA0 + 16;
  const __bf16* gA0 =
      xb + (size_t)(slotArr[rA0] >> 1) * H + (((lane & 3) ^ ((rA0 >> 1) & 3)) * 8);
  const __bf16* gA1 =
      xb + (size_t)(slotArr[rA1] >> 1) * H + (((lane & 3) ^ ((rA1 >> 1) & 3)) * 8);
  const int rW0 = 16 * w + (lane >> 3), rW1 = rW0 + 8;
  const size_t ew = (size_t)e * II * H + (size_t)(nt * 64) * H;
  const float* gG0 = Wg + ew + (size_t)rW0 * H + (((lane & 7) ^ (rW0 & 7)) * 4);
  const float* gG1 = Wg + ew + (size_t)rW1 * H + (((lane & 7) ^ (rW1 & 7)) * 4);
  const float* gU0 = Wu + ew + (size_t)rW0 * H + (((lane & 7) ^ (rW0 & 7)) * 4);
  const float* gU1 = Wu + ew + (size_t)rW1 * H + (((lane & 7) ^ (rW1 & 7)) * 4);
  const int wm = w >> 1, wn = w & 1;
  const int l15 = lane & 15, lk = lane >> 4;

  f32x4 accG[4][2], accU[4][2];
#pragma unroll
  for (int m = 0; m < 4; m++)
#pragma unroll
    for (int n = 0; n < 2; n++)
#pragma unroll
      for (int i = 0; i < 4; i++) {
        accG[m][n][i] = 0.f;
        accU[m][n][i] = 0.f;
      }

#define GU_STAGE(B, T)                                   \
  {                                                      \
    const int ko = (T) * 32;                             \
    gload16(gA0 + ko, &As[B][(32 * w) * 32]);            \
    gload16(gA1 + ko, &As[B][(32 * w + 16) * 32]);       \
    gload16(gG0 + ko, &Gs[B][(16 * w) * 32]);            \
    gload16(gG1 + ko, &Gs[B][(16 * w + 8) * 32]);        \
    gload16(gU0 + ko, &Us[B][(16 * w) * 32]);            \
    gload16(gU1 + ko, &Us[B][(16 * w + 8) * 32]);        \
  }
#define GU_COMPUTE(B)                                                       \
  {                                                                         \
    bf16x8 aF[4];                                                           \
    _Pragma("unroll") for (int m = 0; m < 4; m++) {                         \
      int r = wm * 64 + m * 16 + l15;                                       \
      aF[m] = *(const bf16x8*)&As[B][r * 32 + ((lk ^ ((r >> 1) & 3)) * 8)]; \
    }                                                                       \
    _Pragma("unroll") for (int n = 0; n < 2; n++) {                         \
      int r = wn * 32 + n * 16 + l15;                                       \
      int cA = (2 * lk) ^ (r & 7), cB = cA ^ 1;                             \
      f32x4 glo = *(const f32x4*)&Gs[B][r * 32 + cA * 4];                   \
      f32x4 ghi = *(const f32x4*)&Gs[B][r * 32 + cB * 4];                   \
      f32x4 ulo = *(const f32x4*)&Us[B][r * 32 + cA * 4];                   \
      f32x4 uhi = *(const f32x4*)&Us[B][r * 32 + cB * 4];                   \
      bf16x8 gF, uF;                                                        \
      _Pragma("unroll") for (int i = 0; i < 4; i++) {                       \
        gF[i] = (__bf16)glo[i];                                             \
        gF[i + 4] = (__bf16)ghi[i];                                         \
        uF[i] = (__bf16)ulo[i];                                             \
        uF[i + 4] = (__bf16)uhi[i];                                         \
      }                                                                     \
      _Pragma("unroll") for (int m = 0; m < 4; m++) {                       \
        accG[m][n] = MFMA_BF16(aF[m], gF, accG[m][n]);                      \
        accU[m][n] = MFMA_BF16(aF[m], uF, accU[m][n]);                      \
      }                                                                     \
    }                                                                       \
  }

  GU_STAGE(0, 0);
  GU_STAGE(1, 1);
  for (int t = 0; t < 31; ++t) {
    VMCNT(6);
    SBAR();
    GU_COMPUTE(t & 1);
    LGK0;
    SBAR();
    if (t + 2 < 32) GU_STAGE(t & 1, t + 2);
  }
  VMCNT(0);
  SBAR();
  GU_COMPUTE(1);

  const int colB = nt * 64 + wn * 32;
#pragma unroll
  for (int m = 0; m < 4; m++)
#pragma unroll
    for (int n = 0; n < 2; n++)
#pragma unroll
      for (int i = 0; i < 4; i++) {
        int row = wm * 64 + m * 16 + lk * 4 + i;
        if (rt * 128 + row < ce) {
          int slot = slotArr[row];
          float g = accG[m][n][i];
          float u = accU[m][n][i];
          float a = (g / (1.f + __expf(-g))) * u;
          act[(size_t)slot * II + colB + n * 16 + l15] = (__bf16)a;
        }
      }
}

// ---------------- pass 2: y = wgt * (act @ Wd^T), split-K x2 ----------------
// BM=128, BN=64, BK=32, 256 thr, global_load_lds staging, vmcnt(4).
__global__ __launch_bounds__(256, 4) void k_down(
    const __bf16* __restrict__ act, const float* __restrict__ Wd,
    const int* __restrict__ perm, const int* __restrict__ cnt,
    const float* __restrict__ wgt, float* __restrict__ yb0,
    float* __restrict__ yb1) {
  __shared__ __bf16 As[2][128 * 32];
  __shared__ float Ws[2][64 * 32];
  __shared__ int slotArr[128];
  const int e = blockIdx.z, nt = blockIdx.x;
  const int rt = blockIdx.y & 7, sk = blockIdx.y >> 3;
  const int ce = cnt[e];
  if (ce <= 0 || rt * 128 >= ce) return;
  const int tid = threadIdx.x, lane = tid & 63, w = tid >> 6;
  if (tid < 128) {
    int ridx = rt * 128 + tid;
    slotArr[tid] = perm[e * CAP + (ridx < ce ? ridx : 0)];
  }
  __syncthreads();
  const int KB = sk * 2048;
  const int rA0 = 32 * w + (lane >> 2), rA1 = rA0 + 16;
  const __bf16* gA0 =
      act + (size_t)slotArr[rA0] * II + KB + (((lane & 3) ^ ((rA0 >> 1) & 3)) * 8);
  const __bf16* gA1 =
      act + (size_t)slotArr[rA1] * II + KB + (((lane & 3) ^ ((rA1 >> 1) & 3)) * 8);
  const int rW0 = 16 * w + (lane >> 3), rW1 = rW0 + 8;
  const float* gW0 = Wd + (size_t)e * H * II + (size_t)(nt * 64 + rW0) * II + KB +
                     (((lane & 7) ^ (rW0 & 7)) * 4);
  const float* gW1 = Wd + (size_t)e * H * II + (size_t)(nt * 64 + rW1) * II + KB +
                     (((lane & 7) ^ (rW1 & 7)) * 4);
  const int wm = w >> 1, wn = w & 1;
  const int l15 = lane & 15, lk = lane >> 4;

  f32x4 acc[4][2];
#pragma unroll
  for (int m = 0; m < 4; m++)
#pragma unroll
    for (int n = 0; n < 2; n++)
#pragma unroll
      for (int i = 0; i < 4; i++) acc[m][n][i] = 0.f;

#define DN_STAGE(B, T)                                   \
  {                                                      \
    const int ko = (T) * 32;                             \
    gload16(gA0 + ko, &As[B][(32 * w) * 32]);            \
    gload16(gA1 + ko, &As[B][(32 * w + 16) * 32]);       \
    gload16(gW0 + ko, &Ws[B][(16 * w) * 32]);            \
    gload16(gW1 + ko, &Ws[B][(16 * w + 8) * 32]);        \
  }
#define DN_COMPUTE(B)                                                       \
  {                                                                         \
    bf16x8 aF[4];                                                           \
    _Pragma("unroll") for (int m = 0; m < 4; m++) {                         \
      int r = wm * 64 + m * 16 + l15;                                       \
      aF[m] = *(const bf16x8*)&As[B][r * 32 + ((lk ^ ((r >> 1) & 3)) * 8)]; \
    }                                                                       \
    _Pragma("unroll") for (int n = 0; n < 2; n++) {                         \
      int r = wn * 32 + n * 16 + l15;                                       \
      int cA = (2 * lk) ^ (r & 7), cB = cA ^ 1;                             \
      f32x4 wlo = *(const f32x4*)&Ws[B][r * 32 + cA * 4];                   \
      f32x4 whi = *(const f32x4*)&Ws[B][r * 32 + cB * 4];                   \
      bf16x8 wF;                                                            \
      _Pragma("unroll") for (int i = 0; i < 4; i++) {                       \
        wF[i] = (__bf16)wlo[i];                                             \
        wF[i + 4] = (__bf16)whi[i];                                         \
      }                                                                     \
      _Pragma("unroll") for (int m = 0; m < 4; m++)                         \
          acc[m][n] = MFMA_BF16(aF[m], wF, acc[m][n]);                      \
    }                                                                       \
  }

  DN_STAGE(0, 0);
  DN_STAGE(1, 1);
  for (int t = 0; t < 63; ++t) {
    VMCNT(4);
    SBAR();
    DN_COMPUTE(t & 1);
    LGK0;
    SBAR();
    if (t + 2 < 64) DN_STAGE(t & 1, t + 2);
  }
  VMCNT(0);
  SBAR();
  DN_COMPUTE(1);

  float* yp = sk ? yb1 : yb0;
  const int colB = nt * 64 + wn * 32;
#pragma unroll
  for (int m = 0; m < 4; m++)
#pragma unroll
    for (int n = 0; n < 2; n++)
#pragma unroll
      for (int i = 0; i < 4; i++) {
        int row = wm * 64 + m * 16 + lk * 4 + i;
        if (rt * 128 + row < ce) {
          int slot = slotArr[row];
          yp[(size_t)slot * H + colB + n * 16 + l15] =
              wgt[slot] * acc[m][n][i];
        }
      }
}

// ---------------- combine ----------
__global__ __launch_bounds__(256) void k_combine(const float* __restrict__ y0p,
                                                 const float* __restrict__ y1p,
                                                 const int* __restrict__ kept,
                                                 float* __restrict__ out) {
  int t = blockIdx.x, tid = threadIdx.x;
  size_t o0 = (size_t)(2 * t) * H, o1 = (size_t)(2 * t + 1) * H;
  f32x4 a, b;
#pragma unroll
  for (int i = 0; i < 4; i++) {
    a[i] = 0.f;
    b[i] = 0.f;
  }
  if (kept[2 * t])
    a = ((const f32x4*)(y0p + o0))[tid] + ((const f32x4*)(y1p + o0))[tid];
  if (kept[2 * t + 1])
    b = ((const f32x4*)(y0p + o1))[tid] + ((const f32x4*)(y1p + o1))[tid];
  ((f32x4*)out)[(size_t)t * 256 + tid] = a + b;
  if (t == 0 && tid == 0) out[(size_t)NTOK * H] = 0.f;  // aux_loss
}

extern "C" void kernel_launch(void* const* d_in, const int* in_sizes, int n_in,
                              void* d_out, int out_size, void* d_ws,
                              size_t ws_size, hipStream_t stream) {
  const float* x = (const float*)d_in[0];
  const float* gw = (const float*)d_in[1];
  const float* erw = (const float*)d_in[2];
  const float* Wg = (const float*)d_in[3];
  const float* Wu = (const float*)d_in[4];
  const float* Wd = (const float*)d_in[5];
  float* out = (float*)d_out;
  char* ws = (char*)d_ws;
  int* eid = (int*)(ws);
  float* wgt = (float*)(ws + (16 << 10));
  int* kept = (int*)(ws + (32 << 10));
  int* cnt = (int*)(ws + (48 << 10));
  int* perm = (int*)(ws + (64 << 10));
  size_t off = 128 << 10;
  __bf16* act = (__bf16*)(ws + off);  // 32 MB
  off += (size_t)NSLOT * II * 2;
  float* yb0 = (float*)(ws + off);  // 16 MB
  off += (size_t)NSLOT * H * 4;
  float* yb1 = (float*)(ws + off);  // 16 MB
  off += (size_t)NSLOT * H * 4;
  __bf16* xb = (__bf16*)(ws + off);  // 4 MB

  k_route<<<NTOK / 4, 256, 0, stream>>>(x, gw, erw, eid, wgt);
  k_scan<<<1, 1024, 0, stream>>>(eid, perm, cnt, kept);
  k_cvtx<<<NTOK * H / 8 / 256, 256, 0, stream>>>(x, xb);
  k_gateup<<<dim3(64, 8, 16), 256, 0, stream>>>(xb, Wg, Wu, perm, cnt, act);
  k_down<<<dim3(16, 16, 16), 256, 0, stream>>>(act, Wd, perm, cnt, wgt, yb0, yb1);
  k_combine<<<NTOK, 256, 0, stream>>>(yb0, yb1, kept, out);
}